// Round 16
// baseline (138.914 us; speedup 1.0000x reference)
//
#include <hip/hip_runtime.h>
#include <hip/hip_fp16.h>

// Problem: inputs (8, 64, 16, 32, 32) fp32, embedding (1024, 64) fp32
#define THW    16384
#define NTOT   131072
#define KDIM   1024
#define CDIM   64
#define QELEMS 8388608          // 8*64*16*32*32
#define LOSS_OFF 8388608
#define IDX_OFF  8388610
#define BN     128              // queries per block

typedef _Float16 half8   __attribute__((ext_vector_type(8)));
typedef _Float16 half4_t __attribute__((ext_vector_type(4)));
typedef float    f32x4   __attribute__((ext_vector_type(4)));

// ---- prep: zero losses; split E into fp16 {hiS, lo} where hiS = 4096*h
// (h = fp16(e), exact exponent shift) and lo = (e-h)*4096. With B-side
// {xh, xres} all six MFMA products land on ONE 4096x scale -> single
// accumulator chain. Layout: Ef[tile][slot][lane][8], slots = {hiS.ch0,
// hiS.ch1, lo.ch0, lo.ch1}; tile = 4 KB, linear in the lane order vq_main
// reads (global_load_lds = wave-uniform base + lane*16).
// me2h[row] = -2048*||e||^2 = 4096*(-0.5||e||^2): seeds the scaled chain.
__global__ __launch_bounds__(256) void vq_prep(const float* __restrict__ emb,
        _Float16* __restrict__ Ef, float* __restrict__ me2h,
        float* __restrict__ out) {
    const int t = threadIdx.x;
    if (blockIdx.x == 0 && t == 0) { out[LOSS_OFF] = 0.f; out[LOSS_OFF + 1] = 0.f; }
    const int ln   = t >> 4;
    const int g    = t & 15;
    const int tile = blockIdx.x;
    const int row  = tile * 16 + ln;
    const int c0   = g * 4;
    float4 v = *(const float4*)(emb + (size_t)row * CDIM + c0);
    const float xs[4] = {v.x, v.y, v.z, v.w};
    half4_t h, l;
    float s = 0.f;
    #pragma unroll
    for (int j = 0; j < 4; ++j) {
        const _Float16 hj = (_Float16)xs[j];
        h[j] = hj * (_Float16)4096.0f;          // exact exponent shift
        l[j] = (_Float16)((xs[j] - (float)hj) * 4096.0f);
        s = fmaf(xs[j], xs[j], s);
    }
    const int ch = c0 >> 5;
    const int lq = (c0 & 31) >> 3;
    const int j0 = c0 & 7;
    const int fl = lq * 16 + ln;
    *(half4_t*)(Ef + (((size_t)tile * 4 + ch)     * 64 + fl) * 8 + j0) = h;
    *(half4_t*)(Ef + (((size_t)tile * 4 + 2 + ch) * 64 + fl) * 8 + j0) = l;
    #pragma unroll
    for (int off = 1; off < 16; off <<= 1) s += __shfl_xor(s, off, 64);
    if (g == 0) me2h[row] = -2048.0f * s;
}

// ---- main: 512-thread blocks (8 waves = 4 wq query-quarters x 2 wk tile
// parities). Halved per-wave register state (Bh/Bl[2][2] = 32 VGPR) lets
// up to 6 waves/SIMD = 24 waves/CU reside (vs 16 in all 4-wave variants) —
// more concurrent MFMA chains to hide the exposed chain+barrier latency
// that every pipe-level lever failed to move. Proven r6/r15 pipeline kept:
// cooperative global_load_lds (1 op/thread/stage -> steady vmcnt(1)),
// 3 x 8 KB buffers + me2l in LDS, lockstep barriers, single-4096x-scale
// 6-MFMA chain, bare-compare fold.
__global__ __launch_bounds__(512, 6) void vq_main(const float* __restrict__ in,
        const float* __restrict__ emb,
        const _Float16* __restrict__ Ef,
        const float* __restrict__ me2h, float* __restrict__ out) {

    __shared__ char smem[35840];
    // phase 1: Xs[128][68] @ 0 (34816 B)
    // loop:    buf0/1/2 @ 0/8192/16384 (8 KB each); me2l @ 24576 (4 KB)
    // post:    bv @ 28672 (512), bj @ 29184 (512) — dead-buffer space;
    //          Q[128][68] @ 0 (gather), idxs @ 34816 (512), wsum @ 35328
    float (*Xs)[68] = (float (*)[68])smem;
    float (*Q)[68]  = (float (*)[68])smem;
    float* bv   = (float*)(smem + 28672);
    int*   bj   = (int*)(smem + 29184);
    int*   idxs = (int*)(smem + 34816);
    float* wsum = (float*)(smem + 35328);
    const char* me2l = (const char*)smem + 24576;

    const int tid  = threadIdx.x;
    const int lane = tid & 63;
    const int w    = tid >> 6;      // 0..7
    const int wk   = w & 1;         // tile parity this wave computes
    const int wq   = w >> 1;        // query quarter (32 q) this wave computes
    const int ln   = lane & 15;
    const int lq   = lane >> 4;

    const int n0   = blockIdx.x * BN;
    const int bb   = n0 >> 14;
    const int thw0 = n0 & (THW - 1);
    const float* inb = in  + (size_t)bb * CDIM * THW + thw0;
    float*      outb = out + (size_t)bb * CDIM * THW + thw0;

    // ---- stage X tile ([n][c] transpose); 512 threads, 16 rows each ----
    {
        const int nl = tid & 127;
        const int hf = tid >> 7;        // 0..3
        #pragma unroll 8
        for (int r = 0; r < 16; ++r) {
            const int c = hf * 16 + r;
            Xs[nl][c] = inb[(size_t)c * THW + nl];
        }
    }
    __syncthreads();

    // ---- B fragments {xh, xres} + ||x||^2 in registers: 2 qg groups ----
    half8 Bh[2][2], Bl[2][2];
    float x2r[2];
    #pragma unroll
    for (int qg = 0; qg < 2; ++qg) {
        const int q = wq * 32 + qg * 16 + ln;
        float s = 0.f;
        #pragma unroll
        for (int ch = 0; ch < 2; ++ch) {
            const float* xp = &Xs[q][ch * 32 + lq * 8];
            const float4 xa = *(const float4*)(xp);
            const float4 xb = *(const float4*)(xp + 4);
            const float xv[8] = {xa.x, xa.y, xa.z, xa.w, xb.x, xb.y, xb.z, xb.w};
            #pragma unroll
            for (int j = 0; j < 8; ++j) {
                const _Float16 h = (_Float16)xv[j];
                Bh[qg][ch][j] = h;
                Bl[qg][ch][j] = (_Float16)(xv[j] - (float)h);   // unscaled residual
                s = fmaf(xv[j], xv[j], s);
            }
        }
        s += __shfl_xor(s, 16, 64);     // fold the 4 lq-quads: full ||x||^2
        s += __shfl_xor(s, 32, 64);
        x2r[qg] = s;
    }
    __syncthreads();    // Xs dead -> smem[0..28K) becomes bufs + me2l

    // me2 -> LDS (4 KB, waves 0..3 only, one 16B chunk per thread).
    // Extra op only in waves 0-3's vmcnt ledger; first WAIT1 retires it
    // together with their stage(0) slice (in-order retirement).
    if (tid < 256)
        __builtin_amdgcn_global_load_lds(
            (const unsigned int*)((const char*)me2h + tid * 16),
            (unsigned int*)(smem + 24576 + tid * 16), 16, 0, 0);

    const char* Efb = (const char*)Ef + (size_t)(w * 1024 + lane * 16);

    float bests[2] = {-3.4e38f, -3.4e38f};
    int   besti[2] = {0, 0};

// stage step K's 8 KB (tiles 2K, 2K+1): 512 threads x 16 B = 1 op/thread
#define STAGE(K, BI)                                                          \
    {   __builtin_amdgcn_global_load_lds(                                     \
            (const unsigned int*)(Efb + (size_t)(K) * 8192),                  \
            (unsigned int*)(smem + (BI) * 8192 + w * 1024), 16, 0, 0);        \
    }

// compute tile kt = 2S + wk: single 4096x-scale chain, bare-compare fold
#define COMPUTE(S, BI)                                                        \
    {   const half8* A = (const half8*)(smem + (BI) * 8192 + wk * 4096);      \
        const half8 ah0 = A[lane];                                            \
        const half8 ah1 = A[64 + lane];                                       \
        const half8 al0 = A[128 + lane];                                      \
        const half8 al1 = A[192 + lane];                                      \
        const int kt = (S) * 2 + wk;                                          \
        const f32x4 e2v = *(const f32x4*)(me2l + kt * 64 + lq * 16);          \
        const int kb = kt * 16;                                               \
        __builtin_amdgcn_s_setprio(1);                                        \
        _Pragma("unroll")                                                     \
        for (int qg = 0; qg < 2; ++qg) {                                      \
            f32x4 acc = e2v;                                                  \
            acc = __builtin_amdgcn_mfma_f32_16x16x32_f16(ah0, Bh[qg][0], acc, 0, 0, 0); \
            acc = __builtin_amdgcn_mfma_f32_16x16x32_f16(ah1, Bh[qg][1], acc, 0, 0, 0); \
            acc = __builtin_amdgcn_mfma_f32_16x16x32_f16(ah0, Bl[qg][0], acc, 0, 0, 0); \
            acc = __builtin_amdgcn_mfma_f32_16x16x32_f16(ah1, Bl[qg][1], acc, 0, 0, 0); \
            acc = __builtin_amdgcn_mfma_f32_16x16x32_f16(al0, Bh[qg][0], acc, 0, 0, 0); \
            acc = __builtin_amdgcn_mfma_f32_16x16x32_f16(al1, Bh[qg][1], acc, 0, 0, 0); \
            _Pragma("unroll")                                                 \
            for (int r = 0; r < 4; ++r) {                                     \
                if (acc[r] > bests[qg]) { bests[qg] = acc[r]; besti[qg] = kb + r; } \
            }                                                                 \
        }                                                                     \
        __builtin_amdgcn_s_setprio(0);                                        \
    }

#define WAIT1 asm volatile("s_waitcnt vmcnt(1)" ::: "memory")
#define WAIT0 asm volatile("s_waitcnt vmcnt(0)" ::: "memory")
#define BAR   __builtin_amdgcn_s_barrier()
#define STEP(S, CB, SB) { WAIT1; BAR; STAGE((S) + 2, SB) COMPUTE(S, CB) }

    // Ledger (per wave, ops): STAGE = 1. Waves 0-3 carry +1 (me2l), retired
    // by their first WAIT1 along with stage(0) (in-order). Steady at step s:
    // outstanding {s, s+1} -> WAIT1 retires s, leaves s+1 in flight; barrier
    // publishes buffer s to all waves; buffer (s+2)%3 was consumed at s-1.
    STAGE(0, 0)
    STAGE(1, 1)
    #pragma unroll 1
    for (int s0 = 0; s0 < 30; s0 += 3) {
        STEP(s0,     0, 2)
        STEP(s0 + 1, 1, 0)
        STEP(s0 + 2, 2, 1)
    }
    WAIT1; BAR; COMPUTE(30, 0)
    WAIT0; BAR; COMPUTE(31, 1)

    besti[0] += lq * 4;     // full code index = kt*16 + lq*4 + r
    besti[1] += lq * 4;

    // ---- wave-internal argmax reduce across the 4 row-quads ----
    #pragma unroll
    for (int qg = 0; qg < 2; ++qg) {
        #pragma unroll
        for (int msk = 16; msk <= 32; msk <<= 1) {
            const float ov = __shfl_xor(bests[qg], msk, 64);
            const int   oi = __shfl_xor(besti[qg], msk, 64);
            if (ov > bests[qg] || (ov == bests[qg] && oi < besti[qg])) {
                bests[qg] = ov; besti[qg] = oi;
            }
        }
    }

    // ---- cross-wave combine: wk=1 publishes, wk=0 merges (x2 in regs) ----
    if (wk == 1 && lq == 0) {
        #pragma unroll
        for (int qg = 0; qg < 2; ++qg) {
            const int q = wq * 32 + qg * 16 + ln;
            bv[q] = bests[qg];
            bj[q] = besti[qg];
        }
    }
    __syncthreads();    // bv/bj visible; all waves done reading bufs

    float lsum = 0.f;
    if (wk == 0 && lq == 0) {
        #pragma unroll
        for (int qg = 0; qg < 2; ++qg) {
            const int q = wq * 32 + qg * 16 + ln;
            const float ov = bv[q];
            const int   oi = bj[q];
            if (ov > bests[qg] || (ov == bests[qg] && oi < besti[qg])) {
                bests[qg] = ov; besti[qg] = oi;
            }
            idxs[q] = besti[qg];
            out[IDX_OFF + n0 + q] = (float)besti[qg];
            // s = bests/4096 ; d = -2*s ; loss term = d + ||x||^2
            lsum += fmaf(-4.8828125e-4f, bests[qg], x2r[qg]);
        }
    }
    #pragma unroll
    for (int off = 32; off > 0; off >>= 1) lsum += __shfl_down(lsum, off, 64);
    if (lane == 0) wsum[w] = lsum;
    __syncthreads();    // idxs + wsum visible
    if (tid == 0) {
        float s = 0.f;
        #pragma unroll
        for (int i = 0; i < 8; ++i) s += wsum[i];
        atomicAdd(&out[LOSS_OFF],     s * (1.0f  / (float)QELEMS));
        atomicAdd(&out[LOSS_OFF + 1], s * (0.25f / (float)QELEMS));
    }

    // ---- epilogue: gather code rows into LDS (Q aliases dead bufs), transpose-write ----
    {
        const int q  = tid >> 2;
        const int pt = tid & 3;
        const float* er = emb + (size_t)idxs[q] * CDIM + pt * 16;
        #pragma unroll
        for (int j = 0; j < 4; ++j) {
            const float4 v = *(const float4*)(er + 4 * j);
            *(float4*)(&Q[q][pt * 16 + 4 * j]) = v;
        }
    }
    __syncthreads();
    {
        const int nl = tid & 127;
        const int cb = tid >> 7;        // 0..3
        #pragma unroll 8
        for (int r = 0; r < 16; ++r) {
            const int c = r * 4 + cb;
            outb[(size_t)c * THW + nl] = Q[nl][c];
        }
    }
#undef STAGE
#undef COMPUTE
#undef WAIT1
#undef WAIT0
#undef BAR
#undef STEP
}

extern "C" void kernel_launch(void* const* d_in, const int* in_sizes, int n_in,
                              void* d_out, int out_size, void* d_ws, size_t ws_size,
                              hipStream_t stream) {
    const float* in  = (const float*)d_in[0];   // (8, 64, 16, 32, 32) fp32
    const float* emb = (const float*)d_in[1];   // (1024, 64) fp32
    float* out = (float*)d_out;
    _Float16* Ef   = (_Float16*)d_ws;                       // 64 tiles * 4 KB = 256 KB
    float*    me2h = (float*)((char*)d_ws + 262144);        // 1024 floats = -2048*||e||^2

    vq_prep<<<KDIM / 16, 256, 0, stream>>>(emb, Ef, me2h, out);
    vq_main<<<NTOT / BN, 512, 0, stream>>>(in, emb, Ef, me2h, out);
}